// Round 1
// baseline (1170.137 us; speedup 1.0000x reference)
//
#include <hip/hip_runtime.h>

#define N_TOK 98
#define HD    32
#define NH    4
#define DIM   128
#define C3    384
#define NWIN  64
#define B_TOT 2048
#define QT    52      // query tile rows (2 tiles cover 98; rows >= 98 padded)
#define SROW  100     // sS row stride (floats)
#define KROW  100     // sKT row stride
#define QROW  52      // sQT row stride
#define VROW  36      // sV row stride
#define SCALE 0.17677669529663687f  // 1/sqrt(32)

// ---------------------------------------------------------------------------
// Kernel A: per-(window, head) attention. Writes pre-projection output
// (b, n, h*32+d) into xattn (= d_out, reused as scratch).
// ---------------------------------------------------------------------------
__global__ __launch_bounds__(320) void attn_kernel(
    const float* __restrict__ x, const int* __restrict__ rpi,
    const float* __restrict__ mask, const float* __restrict__ rpb,
    float* __restrict__ xattn)
{
    __shared__ float sKT[HD][KROW];    // K transposed: [d][j]
    __shared__ float sV [N_TOK][VROW]; // V row-major:  [j][d]
    __shared__ float sQT[HD][QROW];    // Q tile transposed, pre-scaled: [d][i]
    __shared__ float sS [QT][SROW];    // scores / probs

    const int t  = threadIdx.x;
    const int bh = blockIdx.x;
    const int b  = bh >> 2;
    const int h  = bh & 3;
    const int w  = b & (NWIN - 1);     // b % 64

    const float* xb = x + (size_t)b * N_TOK * C3 + h * HD;

    // ---- load K (transposed) and V -------------------------------------
    for (int e = t; e < N_TOK * 8; e += 320) {
        int n  = e >> 3;
        int d4 = (e & 7) << 2;
        const float* px = xb + (size_t)n * C3;
        float4 kv = *(const float4*)(px + DIM + d4);       // which=1
        sKT[d4 + 0][n] = kv.x;
        sKT[d4 + 1][n] = kv.y;
        sKT[d4 + 2][n] = kv.z;
        sKT[d4 + 3][n] = kv.w;
        float4 vv = *(const float4*)(px + 2 * DIM + d4);   // which=2
        *(float4*)&sV[n][d4] = vv;
    }

    for (int qt = 0; qt < 2; ++qt) {
        const int i0 = qt * QT;

        // ---- load Q tile (transposed, * scale); pad rows with zeros ----
        for (int e = t; e < QT * 8; e += 320) {
            int ir = e >> 3;
            int d4 = (e & 7) << 2;
            int i  = i0 + ir;
            float4 qv = make_float4(0.f, 0.f, 0.f, 0.f);
            if (i < N_TOK) qv = *(const float4*)(xb + (size_t)i * C3 + d4);
            sQT[d4 + 0][ir] = qv.x * SCALE;
            sQT[d4 + 1][ir] = qv.y * SCALE;
            sQT[d4 + 2][ir] = qv.z * SCALE;
            sQT[d4 + 3][ir] = qv.w * SCALE;
        }
        __syncthreads();

        // ---- S = Q K^T + bias + mask  (4x4 register tiles) -------------
        for (int tau = t; tau < 13 * 25; tau += 320) {
            int it = tau / 25;
            int jt = tau - it * 25;
            int i4 = it << 2, j4 = jt << 2;
            float acc[4][4] = {{0.f,0.f,0.f,0.f},{0.f,0.f,0.f,0.f},
                               {0.f,0.f,0.f,0.f},{0.f,0.f,0.f,0.f}};
            #pragma unroll 8
            for (int d = 0; d < HD; ++d) {
                float4 q  = *(const float4*)&sQT[d][i4];
                float4 kk = *(const float4*)&sKT[d][j4];
                acc[0][0] += q.x * kk.x; acc[0][1] += q.x * kk.y;
                acc[0][2] += q.x * kk.z; acc[0][3] += q.x * kk.w;
                acc[1][0] += q.y * kk.x; acc[1][1] += q.y * kk.y;
                acc[1][2] += q.y * kk.z; acc[1][3] += q.y * kk.w;
                acc[2][0] += q.z * kk.x; acc[2][1] += q.z * kk.y;
                acc[2][2] += q.z * kk.z; acc[2][3] += q.z * kk.w;
                acc[3][0] += q.w * kk.x; acc[3][1] += q.w * kk.y;
                acc[3][2] += q.w * kk.z; acc[3][3] += q.w * kk.w;
            }
            #pragma unroll
            for (int a = 0; a < 4; ++a) {
                int i = i0 + i4 + a;
                if (i >= N_TOK) continue;
                #pragma unroll
                for (int bb = 0; bb < 4; ++bb) {
                    int j = j4 + bb;
                    if (j >= N_TOK) continue;
                    float bias = rpb[(size_t)rpi[i * N_TOK + j] * NH + h];
                    float mval = mask[((size_t)w * N_TOK + i) * N_TOK + j];
                    sS[i4 + a][j4 + bb] = acc[a][bb] + bias + mval;
                }
            }
        }
        __syncthreads();

        // ---- softmax: 4 lanes per row, nibble shuffle reduce -----------
        {
            int r = t >> 2, s = t & 3;
            bool valid = (r < QT) && (i0 + r < N_TOK);
            float m = -INFINITY;
            if (valid)
                for (int j = s; j < N_TOK; j += 4) m = fmaxf(m, sS[r][j]);
            m = fmaxf(m, __shfl_xor(m, 1));
            m = fmaxf(m, __shfl_xor(m, 2));
            float ssum = 0.f;
            if (valid)
                for (int j = s; j < N_TOK; j += 4) {
                    float e = __expf(sS[r][j] - m);
                    sS[r][j] = e;
                    ssum += e;
                }
            ssum += __shfl_xor(ssum, 1);
            ssum += __shfl_xor(ssum, 2);
            if (valid) {
                float inv = 1.0f / ssum;
                for (int j = s; j < N_TOK; j += 4) sS[r][j] *= inv;
            }
        }
        __syncthreads();

        // ---- O = P V  (2-row x 4-col tiles), write to xattn ------------
        for (int tau = t; tau < 26 * 8; tau += 320) {
            int dt = tau & 7, it2 = tau >> 3;
            int ir = it2 << 1, d4 = dt << 2;
            float a0[4] = {0.f,0.f,0.f,0.f};
            float a1[4] = {0.f,0.f,0.f,0.f};
            for (int j = 0; j < N_TOK; j += 2) {
                float2 p0 = *(const float2*)&sS[ir][j];
                float2 p1 = *(const float2*)&sS[ir + 1][j];
                float4 v0 = *(const float4*)&sV[j][d4];
                float4 v1 = *(const float4*)&sV[j + 1][d4];
                a0[0] += p0.x * v0.x + p0.y * v1.x;
                a0[1] += p0.x * v0.y + p0.y * v1.y;
                a0[2] += p0.x * v0.z + p0.y * v1.z;
                a0[3] += p0.x * v0.w + p0.y * v1.w;
                a1[0] += p1.x * v0.x + p1.y * v1.x;
                a1[1] += p1.x * v0.y + p1.y * v1.y;
                a1[2] += p1.x * v0.z + p1.y * v1.z;
                a1[3] += p1.x * v0.w + p1.y * v1.w;
            }
            int i = i0 + ir;
            size_t base = (size_t)b * N_TOK * DIM + h * HD + d4;
            if (i < N_TOK)
                *(float4*)&xattn[base + (size_t)i * DIM] =
                    make_float4(a0[0], a0[1], a0[2], a0[3]);
            if (i + 1 < N_TOK)
                *(float4*)&xattn[base + (size_t)(i + 1) * DIM] =
                    make_float4(a1[0], a1[1], a1[2], a1[3]);
        }
        __syncthreads();
    }
}

// ---------------------------------------------------------------------------
// Kernel B: in-place projection io = io @ W^T + b. Each block owns 48 rows:
// loads them to LDS first, so in-place is race-free (blocks touch disjoint rows).
// ---------------------------------------------------------------------------
#define RPBLK 48
__global__ __launch_bounds__(256) void proj_kernel(
    const float* __restrict__ wmat, const float* __restrict__ bias,
    float* __restrict__ io, int nrows)
{
    __shared__ float sX[RPBLK][132];
    __shared__ float sW[64][132];
    const int t  = threadIdx.x;
    const int r0 = blockIdx.x * RPBLK;

    for (int e = t; e < RPBLK * 32; e += 256) {
        int rr = e >> 5, k4 = (e & 31) << 2;
        int r = r0 + rr;
        float4 v = make_float4(0.f, 0.f, 0.f, 0.f);
        if (r < nrows) v = *(const float4*)&io[(size_t)r * DIM + k4];
        *(float4*)&sX[rr][k4] = v;
    }

    const int ct = t & 15, rt = t >> 4;
    #define DOT4(ACC, XV, WV) \
        ACC += (XV).x*(WV).x + (XV).y*(WV).y + (XV).z*(WV).z + (XV).w*(WV).w

    for (int cc = 0; cc < 2; ++cc) {
        const int c0 = cc * 64;
        __syncthreads();
        for (int e = t; e < 64 * 32; e += 256) {
            int wr = e >> 5, k4 = (e & 31) << 2;
            *(float4*)&sW[wr][k4] = *(const float4*)&wmat[(size_t)(c0 + wr) * DIM + k4];
        }
        __syncthreads();

        float acc[3][4] = {{0.f,0.f,0.f,0.f},{0.f,0.f,0.f,0.f},{0.f,0.f,0.f,0.f}};
        #pragma unroll 4
        for (int k4 = 0; k4 < DIM; k4 += 4) {
            float4 x0 = *(const float4*)&sX[rt      ][k4];
            float4 x1 = *(const float4*)&sX[rt + 16][k4];
            float4 x2 = *(const float4*)&sX[rt + 32][k4];
            float4 w0 = *(const float4*)&sW[ct      ][k4];
            float4 w1 = *(const float4*)&sW[ct + 16][k4];
            float4 w2 = *(const float4*)&sW[ct + 32][k4];
            float4 w3 = *(const float4*)&sW[ct + 48][k4];
            DOT4(acc[0][0], x0, w0); DOT4(acc[0][1], x0, w1);
            DOT4(acc[0][2], x0, w2); DOT4(acc[0][3], x0, w3);
            DOT4(acc[1][0], x1, w0); DOT4(acc[1][1], x1, w1);
            DOT4(acc[1][2], x1, w2); DOT4(acc[1][3], x1, w3);
            DOT4(acc[2][0], x2, w0); DOT4(acc[2][1], x2, w1);
            DOT4(acc[2][2], x2, w2); DOT4(acc[2][3], x2, w3);
        }
        #pragma unroll
        for (int p = 0; p < 3; ++p) {
            int r = r0 + rt + 16 * p;
            if (r >= nrows) continue;
            #pragma unroll
            for (int q = 0; q < 4; ++q) {
                int c = c0 + ct + 16 * q;
                io[(size_t)r * DIM + c] = acc[p][q] + bias[c];
            }
        }
    }
    #undef DOT4
}

extern "C" void kernel_launch(void* const* d_in, const int* in_sizes, int n_in,
                              void* d_out, int out_size, void* d_ws, size_t ws_size,
                              hipStream_t stream) {
    const float* x    = (const float*)d_in[0];
    const int*   rpi  = (const int*)  d_in[1];
    const float* mask = (const float*)d_in[2];
    const float* rpb  = (const float*)d_in[3];
    const float* pw   = (const float*)d_in[4];
    const float* pb   = (const float*)d_in[5];
    float* out = (float*)d_out;

    attn_kernel<<<B_TOT * NH, 320, 0, stream>>>(x, rpi, mask, rpb, out);

    const int nrows = B_TOT * N_TOK;
    proj_kernel<<<(nrows + RPBLK - 1) / RPBLK, 256, 0, stream>>>(pw, pb, out, nrows);
}

// Round 2
// 618.204 us; speedup vs baseline: 1.8928x; 1.8928x over previous
//
#include <hip/hip_runtime.h>

typedef __attribute__((ext_vector_type(8))) short short8;
typedef __attribute__((ext_vector_type(4))) float f32x4;

#define N_TOK 98
#define HD    32
#define NH    4
#define DIM   128
#define C3    384
#define NWIN  64
#define B_TOT 2048
#define MT    112                    // padded token count (7 x 16)
#define SCALE 0.17677669529663687f   // 1/sqrt(32)

// attn LDS layout (bytes):
//   phase1: sQ [112][40]s @0 (8960), sK [112][40]s @8960 (8960)
//   phase2: sP [112][136]s @0 (30464)  -- aliases sQ/sK after barrier
//   sVT [32][136]s @30464 (8704)
#define SQK    40
#define SPS    136
#define SVS    136
#define K_OFF  8960
#define VT_OFF 30464
#define LDSZ   (VT_OFF + HD*SVS*2)   // 39168

__device__ __forceinline__ short f2bf(float f) {       // RNE fp32->bf16
    unsigned u = __builtin_bit_cast(unsigned, f);
    u += 0x7fffu + ((u >> 16) & 1u);
    return (short)(u >> 16);
}

// ---------------------------------------------------------------------------
// biasD[h][i][j] = rpb[rpi[i][j]*4 + h]  (dense, padded to 112x112, once)
// ---------------------------------------------------------------------------
__global__ void bias_kernel(const int* __restrict__ rpi,
                            const float* __restrict__ rpb,
                            float* __restrict__ biasD) {
    int idx = blockIdx.x * 256 + threadIdx.x;
    if (idx >= NH * MT * MT) return;
    int j = idx % MT, rest = idx / MT;
    int i = rest % MT, h = rest / MT;
    float v = 0.f;
    if (i < N_TOK && j < N_TOK) v = rpb[rpi[i * N_TOK + j] * NH + h];
    biasD[idx] = v;
}

// ---------------------------------------------------------------------------
// Attention: 1 block per (window,head), 448 thr = 7 waves = 7 M-tiles.
// bf16 MFMA 16x16x32 (K = head_dim = 32). Softmax in registers.
// Writes pre-projection O (fp32) into d_out.
// ---------------------------------------------------------------------------
__global__ __launch_bounds__(448) void attn_kernel(
    const float* __restrict__ x, const float* __restrict__ mask,
    const float* __restrict__ biasD, float* __restrict__ xattn)
{
    __shared__ __align__(16) char smem[LDSZ];
    short* sQ  = (short*)smem;
    short* sK  = (short*)(smem + K_OFF);
    short* sP  = (short*)smem;              // aliased after barrier 2
    short* sVT = (short*)(smem + VT_OFF);

    const int t  = threadIdx.x;
    const int bh = blockIdx.x;
    const int b  = bh >> 2, h = bh & 3;
    const int w  = b & (NWIN - 1);
    const float* xb = x + (size_t)b * N_TOK * C3;

    // ---- stage Q (scaled), K as bf16 [token][d]; pad rows 98..111 = 0 ----
    for (int e = t; e < MT * 8; e += 448) {
        int row = e >> 3, d4 = (e & 7) << 2;
        unsigned long long qp = 0ull, kp = 0ull;
        if (row < N_TOK) {
            const float* p = xb + row * C3 + h * HD + d4;
            float4 qv = *(const float4*)p;
            float4 kv = *(const float4*)(p + DIM);
            qp =  (unsigned long long)(unsigned short)f2bf(qv.x * SCALE)
               | ((unsigned long long)(unsigned short)f2bf(qv.y * SCALE) << 16)
               | ((unsigned long long)(unsigned short)f2bf(qv.z * SCALE) << 32)
               | ((unsigned long long)(unsigned short)f2bf(qv.w * SCALE) << 48);
            kp =  (unsigned long long)(unsigned short)f2bf(kv.x)
               | ((unsigned long long)(unsigned short)f2bf(kv.y) << 16)
               | ((unsigned long long)(unsigned short)f2bf(kv.z) << 32)
               | ((unsigned long long)(unsigned short)f2bf(kv.w) << 48);
        }
        *(unsigned long long*)&sQ[row * SQK + d4] = qp;
        *(unsigned long long*)&sK[row * SQK + d4] = kp;
    }
    // ---- stage V transposed: sVT[d][j] ----
    for (int e = t; e < N_TOK * 8; e += 448) {
        int j = e >> 3, d4 = (e & 7) << 2;
        float4 vv = *(const float4*)(xb + j * C3 + 2 * DIM + h * HD + d4);
        sVT[(d4 + 0) * SVS + j] = f2bf(vv.x);
        sVT[(d4 + 1) * SVS + j] = f2bf(vv.y);
        sVT[(d4 + 2) * SVS + j] = f2bf(vv.z);
        sVT[(d4 + 3) * SVS + j] = f2bf(vv.w);
    }
    for (int e = t; e < HD * (SVS - N_TOK); e += 448) {   // zero j>=98 pad
        int d = e / (SVS - N_TOK), j = N_TOK + e % (SVS - N_TOK);
        sVT[d * SVS + j] = 0;
    }
    __syncthreads();

    const int lane = t & 63;
    const int c = lane & 15, q = lane >> 4;
    const int mtile = t >> 6;            // 0..6
    const int m0 = mtile * 16;

    // ---- S = Q K^T : 7 MFMAs ----
    short8 afrag = *(const short8*)&sQ[(m0 + c) * SQK + q * 8];
    f32x4 acc[7];
    #pragma unroll
    for (int nt = 0; nt < 7; ++nt) {
        f32x4 z = {0.f, 0.f, 0.f, 0.f};
        short8 bfrag = *(const short8*)&sK[(nt * 16 + c) * SQK + q * 8];
        acc[nt] = __builtin_amdgcn_mfma_f32_16x16x32_bf16(afrag, bfrag, z, 0, 0, 0);
    }
    __syncthreads();   // everyone done reading sQ/sK; sP may now overwrite

    // ---- bias + mask + register softmax (rows = q*4+r of this M-tile) ----
    float S[7][4];
    float mx[4] = {-1e30f, -1e30f, -1e30f, -1e30f};
    #pragma unroll
    for (int nt = 0; nt < 7; ++nt) {
        int j = nt * 16 + c;
        #pragma unroll
        for (int r = 0; r < 4; ++r) {
            int i = m0 + q * 4 + r;
            float v = acc[nt][r] + biasD[(h * MT + i) * MT + j];
            if (j < N_TOK && i < N_TOK)
                v += mask[((size_t)w * N_TOK + i) * N_TOK + j];
            if (j >= N_TOK) v = -1e30f;
            S[nt][r] = v;
            mx[r] = fmaxf(mx[r], v);
        }
    }
    #pragma unroll
    for (int r = 0; r < 4; ++r) {
        float m = mx[r];
        m = fmaxf(m, __shfl_xor(m, 1));
        m = fmaxf(m, __shfl_xor(m, 2));
        m = fmaxf(m, __shfl_xor(m, 4));
        m = fmaxf(m, __shfl_xor(m, 8));
        mx[r] = m;
    }
    float sm[4] = {0.f, 0.f, 0.f, 0.f};
    #pragma unroll
    for (int nt = 0; nt < 7; ++nt)
        #pragma unroll
        for (int r = 0; r < 4; ++r) {
            float e = (S[nt][r] > -1e29f) ? __expf(S[nt][r] - mx[r]) : 0.f;
            S[nt][r] = e;
            sm[r] += e;
        }
    float inv[4];
    #pragma unroll
    for (int r = 0; r < 4; ++r) {
        float s = sm[r];
        s += __shfl_xor(s, 1);
        s += __shfl_xor(s, 2);
        s += __shfl_xor(s, 4);
        s += __shfl_xor(s, 8);
        inv[r] = 1.0f / s;   // normalization deferred to O epilogue
    }

    // ---- write P (unnormalized, bf16) to own rows of sP ----
    #pragma unroll
    for (int nt = 0; nt < 7; ++nt)
        #pragma unroll
        for (int r = 0; r < 4; ++r)
            sP[(m0 + q * 4 + r) * SPS + nt * 16 + c] = f2bf(S[nt][r]);
    // zero k-pad cols 112..127 of own rows (lane: row m0+c, 4 cols)
    #pragma unroll
    for (int kk = 0; kk < 4; ++kk)
        sP[(m0 + c) * SPS + 112 + q * 4 + kk] = 0;

    // ---- O = P V : 4 K-tiles x 2 N-tiles (reads own rows only) ----
    f32x4 oacc[2] = {{0.f,0.f,0.f,0.f}, {0.f,0.f,0.f,0.f}};
    #pragma unroll
    for (int kt = 0; kt < 4; ++kt) {
        short8 pa = *(const short8*)&sP[(m0 + c) * SPS + kt * 32 + q * 8];
        #pragma unroll
        for (int n2 = 0; n2 < 2; ++n2) {
            short8 vb = *(const short8*)&sVT[(n2 * 16 + c) * SVS + kt * 32 + q * 8];
            oacc[n2] = __builtin_amdgcn_mfma_f32_16x16x32_bf16(pa, vb, oacc[n2], 0, 0, 0);
        }
    }
    #pragma unroll
    for (int n2 = 0; n2 < 2; ++n2)
        #pragma unroll
        for (int r = 0; r < 4; ++r) {
            int i = m0 + q * 4 + r;
            if (i < N_TOK)
                xattn[((size_t)b * N_TOK + i) * DIM + h * HD + n2 * 16 + c]
                    = oacc[n2][r] * inv[r];
        }
}

// ---------------------------------------------------------------------------
// Projection (in-place on d_out): out = O @ W^T + b, bf16 MFMA.
// Block owns 112 rows (stages them first -> race-free). 448 thr = 7 M-tiles.
// ---------------------------------------------------------------------------
#define PR 112
__global__ __launch_bounds__(448) void proj_kernel(
    const float* __restrict__ wmat, const float* __restrict__ bias,
    float* __restrict__ io)
{
    __shared__ short sX[PR][136];
    __shared__ short sW[DIM][136];
    const int t = threadIdx.x;
    const size_t r0 = (size_t)blockIdx.x * PR;

    for (int e = t; e < PR * 32; e += 448) {
        int rr = e >> 5, k4 = (e & 31) << 2;
        float4 v = *(const float4*)&io[(r0 + rr) * DIM + k4];
        sX[rr][k4 + 0] = f2bf(v.x);
        sX[rr][k4 + 1] = f2bf(v.y);
        sX[rr][k4 + 2] = f2bf(v.z);
        sX[rr][k4 + 3] = f2bf(v.w);
    }
    for (int e = t; e < DIM * 32; e += 448) {
        int rr = e >> 5, k4 = (e & 31) << 2;
        float4 v = *(const float4*)&wmat[rr * DIM + k4];
        sW[rr][k4 + 0] = f2bf(v.x);
        sW[rr][k4 + 1] = f2bf(v.y);
        sW[rr][k4 + 2] = f2bf(v.z);
        sW[rr][k4 + 3] = f2bf(v.w);
    }
    __syncthreads();   // all global reads of io done before in-place writes

    const int lane = t & 63;
    const int c = lane & 15, q = lane >> 4;
    const int mt = t >> 6;               // 0..6

    float bcol[8];
    #pragma unroll
    for (int nt = 0; nt < 8; ++nt) bcol[nt] = bias[nt * 16 + c];

    f32x4 acc[8];
    #pragma unroll
    for (int nt = 0; nt < 8; ++nt) acc[nt] = (f32x4){0.f, 0.f, 0.f, 0.f};

    #pragma unroll
    for (int kt = 0; kt < 4; ++kt) {
        short8 a = *(const short8*)&sX[mt * 16 + c][kt * 32 + q * 8];
        #pragma unroll
        for (int nt = 0; nt < 8; ++nt) {
            short8 bb = *(const short8*)&sW[nt * 16 + c][kt * 32 + q * 8];
            acc[nt] = __builtin_amdgcn_mfma_f32_16x16x32_bf16(a, bb, acc[nt], 0, 0, 0);
        }
    }
    #pragma unroll
    for (int nt = 0; nt < 8; ++nt)
        #pragma unroll
        for (int r = 0; r < 4; ++r)
            io[(r0 + mt * 16 + q * 4 + r) * DIM + nt * 16 + c] = acc[nt][r] + bcol[nt];
}

extern "C" void kernel_launch(void* const* d_in, const int* in_sizes, int n_in,
                              void* d_out, int out_size, void* d_ws, size_t ws_size,
                              hipStream_t stream) {
    const float* x    = (const float*)d_in[0];
    const int*   rpi  = (const int*)  d_in[1];
    const float* mask = (const float*)d_in[2];
    const float* rpb  = (const float*)d_in[3];
    const float* pw   = (const float*)d_in[4];
    const float* pb   = (const float*)d_in[5];
    float* out   = (float*)d_out;
    float* biasD = (float*)d_ws;     // 4*112*112*4 = 200704 B

    bias_kernel<<<(NH * MT * MT + 255) / 256, 256, 0, stream>>>(rpi, rpb, biasD);
    attn_kernel<<<B_TOT * NH, 448, 0, stream>>>(x, mask, biasD, out);
    proj_kernel<<<(B_TOT * N_TOK) / PR, 448, 0, stream>>>(pw, pb, out);
}